// Round 4
// baseline (825.424 us; speedup 1.0000x reference)
//
#include <hip/hip_runtime.h>

// GraphSAGE 3-layer, fp32.
// Linearity: segsum(Wm@concat(nf[src],ef)) == Wm_n@segsum(nf[src]) + Wm_e@segsum(ef) + deg*bm
// R3: on-device CSR + atomic-free gather aggregations (912 us).
// R4/R5: fp32 VALU GEMM rewrite -> REGRESSED (stall-bound, VGPR=136).
// R6: fp16x2 split MFMA GEMM (hihi+hilo+lohi) -> 824 us. Inferred mgemm share
// ~410 us (~6% MfmaUtil): A-tile LDS reads are an 8-WAY bank conflict
// (row stride 64B -> bank-set=(row&1)*4+g, 8 even rows collide), and 2
// barriers per k-step drain the pipe.
// R7 (this): (a) XOR-swizzle 16B chunks: c' = c ^ ((row>>1)&3) -> 2-way (free);
// (b) double-buffered LDS (2x24KB), ONE barrier per k-step; (c) hoisted
// addresses + fully unrolled k-loop (segment select folds at compile time).

#define NN 50000
#define NE 800000
#define NIN 64
#define EDIM_ 64
#define HID_ 152
#define NOUT 64
#define PADN 50176   // 49 * 1024, scan-friendly padding of NN

typedef float f4v __attribute__((ext_vector_type(4)));
typedef _Float16 h8v __attribute__((ext_vector_type(8)));
typedef _Float16 h4v __attribute__((ext_vector_type(4)));

// ---------------- histogram: integer in-degree ----------------
__global__ __launch_bounds__(256) void hist_kernel(const int* __restrict__ dst,
                                                   int* __restrict__ ideg) {
    int e = blockIdx.x * 256 + threadIdx.x;
    if (e < NE) atomicAdd(&ideg[dst[e]], 1);
}

// ---------------- exclusive scan, 3 kernels ----------------
__global__ __launch_bounds__(256) void scan1_kernel(const int* __restrict__ in,
                                                    int* __restrict__ out,
                                                    int* __restrict__ bsum) {
    __shared__ int ws[4];
    int t = threadIdx.x;
    int base = blockIdx.x * 1024 + t * 4;
    int a0 = in[base], a1 = in[base + 1], a2 = in[base + 2], a3 = in[base + 3];
    int s = a0 + a1 + a2 + a3;
    int lane = t & 63, wid = t >> 6;
    int v = s;
#pragma unroll
    for (int d = 1; d < 64; d <<= 1) {
        int u = __shfl_up(v, d);
        if (lane >= d) v += u;
    }
    if (lane == 63) ws[wid] = v;
    __syncthreads();
    int wofs = 0;
    if (wid > 0) wofs += ws[0];
    if (wid > 1) wofs += ws[1];
    if (wid > 2) wofs += ws[2];
    int excl = wofs + v - s;
    out[base] = excl;
    out[base + 1] = excl + a0;
    out[base + 2] = excl + a0 + a1;
    out[base + 3] = excl + a0 + a1 + a2;
    if (t == 255) bsum[blockIdx.x] = wofs + v;
}

__global__ __launch_bounds__(64) void scan2_kernel(int* __restrict__ bsum, int nb) {
    int t = threadIdx.x;
    int orig = (t < nb) ? bsum[t] : 0;
    int v = orig;
#pragma unroll
    for (int d = 1; d < 64; d <<= 1) {
        int u = __shfl_up(v, d);
        if (t >= d) v += u;
    }
    if (t < nb) bsum[t] = v - orig;
}

__global__ __launch_bounds__(256) void scan3_kernel(int* __restrict__ out,
                                                    const int* __restrict__ bsum) {
    int base = blockIdx.x * 1024 + threadIdx.x * 4;
    int b = bsum[blockIdx.x];
    out[base] += b; out[base + 1] += b; out[base + 2] += b; out[base + 3] += b;
}

// ---------------- scatter edges into CSR order ----------------
__global__ __launch_bounds__(256) void scatter_edges_kernel(const int* __restrict__ src,
                                                            const int* __restrict__ dst,
                                                            int* __restrict__ cursor,
                                                            int* __restrict__ csr_nf,
                                                            int* __restrict__ csr_ef) {
    int e = blockIdx.x * 256 + threadIdx.x;
    if (e >= NE) return;
    int d = dst[e];
    int pos = atomicAdd(&cursor[d], 1);
    csr_nf[pos] = src[e];
    csr_ef[pos] = e;
}

// ---------------- gather-sum aggregation ----------------
template <int F>
__global__ __launch_bounds__(256) void agg_kernel(const float* __restrict__ table,
                                                  const int* __restrict__ rows,
                                                  const int* __restrict__ off,
                                                  float* __restrict__ out) {
    constexpr int C = F / 4;          // float4 chunks per row
    constexpr int NPW = 64 / C;       // nodes per wave
    int t = threadIdx.x;
    int lane = t & 63, wid = t >> 6;
    int sub = lane / C;
    int ch = lane - sub * C;
    int n = (blockIdx.x * 4 + wid) * NPW + sub;
    if (sub >= NPW || n >= NN) return;
    int s = off[n], e = off[n + 1];
    float ax0 = 0.f, ax1 = 0.f, ax2 = 0.f, ax3 = 0.f;
    float bx0 = 0.f, bx1 = 0.f, bx2 = 0.f, bx3 = 0.f;
    int i = s;
    for (; i + 1 < e; i += 2) {
        int r0 = rows[i], r1 = rows[i + 1];
        float4 v0 = *(const float4*)(table + (size_t)r0 * F + ch * 4);
        float4 v1 = *(const float4*)(table + (size_t)r1 * F + ch * 4);
        ax0 += v0.x; ax1 += v0.y; ax2 += v0.z; ax3 += v0.w;
        bx0 += v1.x; bx1 += v1.y; bx2 += v1.z; bx3 += v1.w;
    }
    if (i < e) {
        int r0 = rows[i];
        float4 v0 = *(const float4*)(table + (size_t)r0 * F + ch * 4);
        ax0 += v0.x; ax1 += v0.y; ax2 += v0.z; ax3 += v0.w;
    }
    float4 r;
    r.x = ax0 + bx0; r.y = ax1 + bx1; r.z = ax2 + bx2; r.w = ax3 + bx3;
    *(float4*)(out + (size_t)n * F + ch * 4) = r;
}

// ---------------- W pre-split: fp32 -> padded hi/lo fp16 ----------------
__global__ __launch_bounds__(256) void wsplit_kernel(const float* __restrict__ W,
                                                     _Float16* __restrict__ hi,
                                                     _Float16* __restrict__ lo,
                                                     int NT, int Kin1, int K1P,
                                                     int Kin2, int KTP, int total) {
    int e = blockIdx.x * 256 + threadIdx.x;
    if (e >= total) return;
    int n = e / KTP, k = e - n * KTP;
    float v = 0.f;
    if (n < NT) {
        int s = -1;
        if (k < K1P) { if (k < Kin1) s = k; }
        else { int k2 = k - K1P; if (k2 < Kin2) s = Kin1 + k2; }
        if (s >= 0) v = W[(size_t)n * (Kin1 + Kin2) + s];
    }
    _Float16 h = (_Float16)v;
    hi[e] = h;
    lo[e] = (_Float16)(v - (float)h);
}

// ---------------- fp16x2-split MFMA GEMM with fused epilogue ----------------
// out[M x NT] = concat(X1[MxK1], X2[MxK2]) @ W^T + epilogue, 3-product split.
// Block 128(M) x 64(N), 4 waves of 64x32, mfma_f32_16x16x32_f16, K-step 32.
// LDS double-buffered: 2 x (Ahi 8K | Alo 8K | Bhi 4K | Blo 4K) = 48 KB.
// 16B chunks XOR-swizzled (c ^= (row>>1)&3): A-read 8-way conflict -> 2-way.
template <int K1P, int K2P, int K1, int K2, int NT, bool MSG>
__global__ __launch_bounds__(256, 3) void mgemm_kernel(const float* __restrict__ X1,
                                                       const float* __restrict__ X2,
                                                       const _Float16* __restrict__ Whi,
                                                       const _Float16* __restrict__ Wlo,
                                                       const float* __restrict__ bias,
                                                       const int* __restrict__ off,
                                                       float* __restrict__ out) {
    constexpr int KTP = K1P + K2P;     // multiple of 32
    constexpr int NKS = KTP / 32;
    __shared__ _Float16 sm[2][12288];  // per buf: Ahi 0 | Alo 4096 | Bhi 8192 | Blo 10240

    const int t = threadIdx.x;
    const int m0 = blockIdx.x * 128;
    const int n0 = blockIdx.y * 64;

    // ---- staging geometry ----
    // A: thread t -> rows ar+32i (i=0..3), half-chunk hc = t&7 (4 halves = 8B).
    // B: thread t -> row br = t>>2, chunk cb = t&3 (8 halves = 16B). Padded, no guards.
    const int ar = t >> 3;
    const int hc = t & 7;
    const int akc = hc * 4;            // k offset (floats/halves)
    const int br = t >> 2;
    const int cb = t & 3;

    int awofs[4];
#pragma unroll
    for (int i = 0; i < 4; ++i) {
        const int row = ar + 32 * i;
        awofs[i] = row * 32 + (((hc >> 1) ^ ((row >> 1) & 3)) * 8) + (hc & 1) * 4;
    }
    const int bwofs = br * 32 + ((cb ^ ((br >> 1) & 3)) * 8);

    const _Float16* wph = Whi + (size_t)(n0 + br) * KTP + cb * 8;
    const _Float16* wpl = Wlo + (size_t)(n0 + br) * KTP + cb * 8;

    const float* arp1[4];
    const float* arp2[4];
    bool rok[4];
#pragma unroll
    for (int i = 0; i < 4; ++i) {
        const int row = m0 + ar + 32 * i;
        rok[i] = row < NN;
        arp1[i] = X1 + (size_t)row * K1;
        arp2[i] = X2 + (size_t)row * K2;
    }

    // ---- compute geometry: wave wid at (wm,wn) of 2x2; wave tile 64(M)x32(N) ----
    const int lane = t & 63, wid = t >> 6;
    const int wm = wid >> 1, wn = wid & 1;
    const int lr = lane & 15, g = lane >> 4;
    int arofs[4], brofs[2];
#pragma unroll
    for (int mf = 0; mf < 4; ++mf) {
        const int row = wm * 64 + mf * 16 + lr;
        arofs[mf] = row * 32 + ((g ^ ((row >> 1) & 3)) * 8);
    }
#pragma unroll
    for (int nf = 0; nf < 2; ++nf) {
        const int row = wn * 32 + nf * 16 + lr;
        brofs[nf] = row * 32 + ((g ^ ((row >> 1) & 3)) * 8);
    }

    f4v ax[4];
    h8v bxh, bxl;
    f4v acc[4][2] = {};

    auto loadA = [&](const float* const arp[4], const int Ka, const int kb) {
        const int kg = kb + akc;
        const bool kok = kg < Ka;      // folds when kb+28 < Ka is provable
        const f4v z = {0.f, 0.f, 0.f, 0.f};
#pragma unroll
        for (int i = 0; i < 4; ++i)
            ax[i] = (kok && rok[i]) ? *(const f4v*)(arp[i] + kg) : z;
    };
    auto loadT = [&](int k0) {
        if (k0 < K1P) loadA(arp1, K1, k0);
        else          loadA(arp2, K2, k0 - K1P);
        bxh = *(const h8v*)(wph + k0);
        bxl = *(const h8v*)(wpl + k0);
    };
    auto storeT = [&](int buf) {
        _Float16* s0 = &sm[buf][0];
#pragma unroll
        for (int i = 0; i < 4; ++i) {
            h4v hi, lo;
#pragma unroll
            for (int j = 0; j < 4; ++j) {
                float v = ax[i][j];
                _Float16 h = (_Float16)v;
                hi[j] = h;
                lo[j] = (_Float16)(v - (float)h);
            }
            *(h4v*)(s0 + awofs[i]) = hi;
            *(h4v*)(s0 + 4096 + awofs[i]) = lo;
        }
        *(h8v*)(s0 + 8192 + bwofs) = bxh;
        *(h8v*)(s0 + 10240 + bwofs) = bxl;
    };

    loadT(0);
    storeT(0);
    __syncthreads();

#pragma unroll
    for (int s = 0; s < NKS; ++s) {
        if (s + 1 < NKS) loadT((s + 1) * 32);   // global->reg, drains under MFMA
        const _Float16* s0 = &sm[s & 1][0];
        h8v ah[4], al[4], bh[2], bl[2];
#pragma unroll
        for (int mf = 0; mf < 4; ++mf) {
            ah[mf] = *(const h8v*)(s0 + arofs[mf]);
            al[mf] = *(const h8v*)(s0 + 4096 + arofs[mf]);
        }
#pragma unroll
        for (int nf = 0; nf < 2; ++nf) {
            bh[nf] = *(const h8v*)(s0 + 8192 + brofs[nf]);
            bl[nf] = *(const h8v*)(s0 + 10240 + brofs[nf]);
        }
#pragma unroll
        for (int mf = 0; mf < 4; ++mf)
#pragma unroll
            for (int nf = 0; nf < 2; ++nf) {
                acc[mf][nf] = __builtin_amdgcn_mfma_f32_16x16x32_f16(ah[mf], bh[nf], acc[mf][nf], 0, 0, 0);
                acc[mf][nf] = __builtin_amdgcn_mfma_f32_16x16x32_f16(ah[mf], bl[nf], acc[mf][nf], 0, 0, 0);
                acc[mf][nf] = __builtin_amdgcn_mfma_f32_16x16x32_f16(al[mf], bh[nf], acc[mf][nf], 0, 0, 0);
            }
        if (s + 1 < NKS) {
            storeT((s + 1) & 1);   // other buffer: no conflict with current reads
            __syncthreads();       // ONE barrier per k-step
        }
    }

    // ---- epilogue (C layout: col = lane&15, row = (lane>>4)*4 + reg; m89) ----
#pragma unroll
    for (int mf = 0; mf < 4; ++mf) {
#pragma unroll
        for (int r = 0; r < 4; ++r) {
            const int m = m0 + wm * 64 + mf * 16 + g * 4 + r;
            if (m >= NN) continue;
            float dv = 0.f, inv = 0.f;
            if (MSG) {
                dv = (float)(off[m + 1] - off[m]);
                inv = 1.0f / fmaxf(dv, 1.0f);
            }
#pragma unroll
            for (int nf = 0; nf < 2; ++nf) {
                const int n = n0 + wn * 32 + nf * 16 + lr;
                if (n >= NT) continue;
                const float a = acc[mf][nf][r];
                const float val = MSG ? (a + dv * bias[n]) * inv
                                      : fmaxf(a + bias[n], 0.0f);
                out[(size_t)m * NT + n] = val;
            }
        }
    }
}

extern "C" void kernel_launch(void* const* d_in, const int* in_sizes, int n_in,
                              void* d_out, int out_size, void* d_ws, size_t ws_size,
                              hipStream_t stream) {
    const float* nfeats = (const float*)d_in[0];
    const float* efeats = (const float*)d_in[1];
    const float* Wm1 = (const float*)d_in[2];
    const float* bm1 = (const float*)d_in[3];
    const float* Wa1 = (const float*)d_in[4];
    const float* ba1 = (const float*)d_in[5];
    const float* Wm2 = (const float*)d_in[6];
    const float* bm2 = (const float*)d_in[7];
    const float* Wa2 = (const float*)d_in[8];
    const float* ba2 = (const float*)d_in[9];
    const float* Wm3 = (const float*)d_in[10];
    const float* bm3 = (const float*)d_in[11];
    const float* Wa3 = (const float*)d_in[12];
    const float* ba3 = (const float*)d_in[13];
    const int* src = (const int*)d_in[14];
    const int* dst = (const int*)d_in[15];
    float* out = (float*)d_out;

    // workspace layout (4-byte units)
    int* iws = (int*)d_ws;
    int* ideg   = iws;                  // PADN
    int* off    = iws + PADN;           // PADN
    int* cursor = iws + 2 * PADN;       // PADN
    int* csr_nf = iws + 3 * PADN;       // NE
    int* csr_ef = csr_nf + NE;          // NE
    float* B = (float*)(csr_ef + NE);   // NN*64  = 3,200,000
    float* P = B + 3200000;             // NN*152 = 7,600,000
    float* Q = P + 7600000;             // NN*152
    float* R = Q + 7600000;             // NN*152
    // split weights (halves), ~0.8 MB appended after R
    _Float16* w1h = (_Float16*)(R + 7600000);
    _Float16* w1l = w1h + 24576;        // 192*128
    _Float16* w2h = w1l + 24576;
    _Float16* w2l = w2h + 43008;        // 192*224
    _Float16* w3h = w2l + 43008;
    _Float16* w3l = w3h + 43008;        // 192*224
    _Float16* w4h = w3l + 43008;
    _Float16* w4l = w4h + 61440;        // 192*320
    _Float16* w5h = w4l + 61440;
    _Float16* w5l = w5h + 14336;        // 64*224
    _Float16* w6h = w5l + 14336;
    _Float16* w6l = w6h + 14336;        // 64*224

    const int BLK = 256;
    auto cdiv = [](long long a, long long b) { return (int)((a + b - 1) / b); };
    dim3 g152(cdiv(NN, 128), 3);   // N pad 192
    dim3 g64(cdiv(NN, 128), 1);
    const int NB = PADN / 1024;  // 49

    // ---- split weights (independent of graph data) ----
    wsplit_kernel<<<96,  BLK, 0, stream>>>(Wm1, w1h, w1l, 152, 64, 64, 64, 128, 24576);
    wsplit_kernel<<<168, BLK, 0, stream>>>(Wa1, w2h, w2l, 152, 64, 64, 152, 224, 43008);
    wsplit_kernel<<<168, BLK, 0, stream>>>(Wm2, w3h, w3l, 152, 152, 160, 64, 224, 43008);
    wsplit_kernel<<<240, BLK, 0, stream>>>(Wa2, w4h, w4l, 152, 152, 160, 152, 320, 61440);
    wsplit_kernel<<<56,  BLK, 0, stream>>>(Wm3, w5h, w5l, 64, 152, 160, 64, 224, 14336);
    wsplit_kernel<<<56,  BLK, 0, stream>>>(Wa3, w6h, w6l, 64, 152, 160, 64, 224, 14336);

    // ---- CSR build ----
    hipMemsetAsync(ideg, 0, (size_t)PADN * 4, stream);
    hist_kernel<<<cdiv(NE, BLK), BLK, 0, stream>>>(dst, ideg);
    scan1_kernel<<<NB, 256, 0, stream>>>(ideg, off, cursor);
    scan2_kernel<<<1, 64, 0, stream>>>(cursor, NB);
    scan3_kernel<<<NB, 256, 0, stream>>>(off, cursor);
    hipMemcpyAsync(cursor, off, (size_t)NN * 4, hipMemcpyDeviceToDevice, stream);
    scatter_edges_kernel<<<cdiv(NE, BLK), BLK, 0, stream>>>(src, dst, cursor, csr_nf, csr_ef);

    // ---- layer-invariant: B = segsum(ef) ----
    agg_kernel<EDIM_><<<cdiv(NN, 16), BLK, 0, stream>>>(efeats, csr_ef, off, B);

    // ---- layer 1 ----
    agg_kernel<NIN><<<cdiv(NN, 16), BLK, 0, stream>>>(nfeats, csr_nf, off, P);
    mgemm_kernel<64, 64, 64, 64, HID_, true><<<g152, BLK, 0, stream>>>(P, B, w1h, w1l, bm1, off, Q);
    mgemm_kernel<64, 160, 64, 152, HID_, false><<<g152, BLK, 0, stream>>>(nfeats, Q, w2h, w2l, ba1, off, R);  // h1 = R

    // ---- layer 2 ----
    agg_kernel<HID_><<<cdiv(NN, 4), BLK, 0, stream>>>(R, csr_nf, off, P);
    mgemm_kernel<160, 64, 152, 64, HID_, true><<<g152, BLK, 0, stream>>>(P, B, w3h, w3l, bm2, off, Q);
    mgemm_kernel<160, 160, 152, 152, HID_, false><<<g152, BLK, 0, stream>>>(R, Q, w4h, w4l, ba2, off, P);     // h2 = P

    // ---- layer 3 ----
    agg_kernel<HID_><<<cdiv(NN, 4), BLK, 0, stream>>>(P, csr_nf, off, Q);
    mgemm_kernel<160, 64, 152, 64, NOUT, true><<<g64, BLK, 0, stream>>>(Q, B, w5h, w5l, bm3, off, R);         // hn3 = R
    mgemm_kernel<160, 64, 152, 64, NOUT, false><<<g64, BLK, 0, stream>>>(P, R, w6h, w6l, ba3, off, out);
}